// Round 9
// baseline (370.439 us; speedup 1.0000x reference)
//
#include <hip/hip_runtime.h>

typedef __attribute__((ext_vector_type(8))) short s16x8;
typedef __attribute__((ext_vector_type(4))) short s16x4;
typedef __attribute__((ext_vector_type(4))) float f32x4;

#define MFMA16(a,b,c) __builtin_amdgcn_mfma_f32_16x16x32_bf16((a),(b),(c),0,0,0)

// async global->LDS, 16B per lane; LDS dest is wave-uniform base + lane*16
#define GLOAD_LDS16(g, l) \
    __builtin_amdgcn_global_load_lds((const __attribute__((address_space(1))) void*)(g), \
                                     (__attribute__((address_space(3))) void*)(l), 16, 0, 0)

__device__ __forceinline__ unsigned short f2bf(float f) {
    unsigned u = __builtin_bit_cast(unsigned, f);
    u = (u + 0x7FFFu + ((u >> 16) & 1u)) >> 16;
    return (unsigned short)u;
}
__device__ __forceinline__ float bf2f(unsigned short v) {
    unsigned u = ((unsigned)v) << 16;
    return __builtin_bit_cast(float, u);
}

// ---------------- ws layout (bytes) ----------------
#define MB ((size_t)1 << 20)
#define WT_OFF   ((size_t)0)        // Wt[384][1024] bf16 (row = mat*128+h)
#define QKV_OFF  (1*MB)             // Q only: [32768][128] bf16 = 8 MB (K/V never materialized)
#define VT0_OFF  (25*MB)            // per-config V image: [seg][16 jt][8 kchunk][128 h][8 key] bf16
#define VT1_OFF  (33*MB)
#define VT2_OFF  (37*MB)
#define VT3_OFF  (39*MB)
#define KG1_OFF  (40*MB)            // per-config K image: [seg][16 jt][16 hchunk][64 key][8 h] bf16
#define KG2_OFF  (44*MB)
#define KG3_OFF  (46*MB)
#define O0_OFF   (47*MB)            // per-config unnormalized O, BF16 packed [seg*1024][128]
#define O1_OFF   (63*MB)
#define O2_OFF   (71*MB)
#define O3_OFF   (75*MB)
#define L0_OFF   (77*MB)            // per-config denominators fp32
#define L1_OFF   (L0_OFF + (size_t)131072)
#define L2_OFF   (L1_OFF + (size_t)65536)
#define L3_OFF   (L2_OFF + (size_t)32768)
#define KI0_OFF  (78*MB)            // c0 K image, 8 MB

// ---------------- W transpose: Wt[mat*128+h][c] = bf16(W[c][h]) ----------------
__global__ __launch_bounds__(256) void k_wt(const float* __restrict__ Wq, const float* __restrict__ Wk,
                                            const float* __restrict__ Wv, unsigned short* __restrict__ Wt) {
    int id = blockIdx.x * 256 + threadIdx.x;
    int mat = id >> 17;
    int rem = id & 131071;
    int h = rem >> 10, c = rem & 1023;
    const float* W = (mat == 0) ? Wq : (mat == 1) ? Wk : Wv;
    Wt[id] = f2bf(W[c * 128 + h]);
}

// ---------------- fused QKV GEMM + gather: writes Q rows and K/V images DIRECTLY ----------------
// [32768 x 1024] @ [1024 x 384]; epilogue scatters K/V from the LDS C-tile into the exact
// fragment-order images the attention kernel stages from (8-key groups never cross a 64-row block).
__global__ __launch_bounds__(256, 2) void k_qkv(const float* __restrict__ x,
                                                const unsigned short* __restrict__ Wt,
                                                char* __restrict__ ws) {
    union SMem {
        struct { float As[64][64]; unsigned short Bs[384][64]; } s;  // 16 KB + 48 KB
        unsigned short Cs[64][392];                                   // epilogue staging, 49 KB
    };
    __shared__ SMem sm;
    float* Asf = &sm.s.As[0][0];
    unsigned short* Bsu = &sm.s.Bs[0][0];
    unsigned short* Q = (unsigned short*)(ws + QKV_OFF);

    const int mt = blockIdx.x;        // 0..511, 64-row m-tile
    const int tid = threadIdx.x, lane = tid & 63, wv = tid >> 6;
    const int quad = lane >> 4, m16 = lane & 15;
    const int wr = wv >> 1, wc = wv & 1;     // wave tile: rows wr*32.., cols wc*192..
    const float* xb = x + (size_t)mt * 64 * 1024;

    f32x4 acc[2][12];
#pragma unroll
    for (int i = 0; i < 2; i++)
#pragma unroll
        for (int j = 0; j < 12; j++) acc[i][j] = (f32x4)0.f;

    for (int kk = 0; kk < 1024; kk += 64) {
        // ---- stage A (x, fp32): 16 KB = 16 insts, 4/wave. phys group = logical ^ (row&7) ----
#pragma unroll
        for (int t = 0; t < 4; t++) {
            int id = wv * 4 + t;                       // 0..15, wave-uniform
            int row = id * 4 + (lane >> 4);
            int gl = (lane & 15) ^ (row & 7);          // logical 16B-group this lane fetches
            GLOAD_LDS16(xb + (size_t)row * 1024 + kk + gl * 4, (char*)Asf + id * 1024);
        }
        // ---- stage B (Wt, bf16): 48 KB = 48 insts, 12/wave. phys group = logical ^ (col&7) ----
#pragma unroll
        for (int t = 0; t < 12; t++) {
            int id = wv * 12 + t;                      // 0..47
            int col = id * 8 + (lane >> 3);
            int gl = (lane & 7) ^ (lane >> 3);         // (col&7) == lane>>3 here
            GLOAD_LDS16(Wt + (size_t)col * 1024 + kk + gl * 8, (char*)Bsu + id * 1024);
        }
        __syncthreads();
        // ---- compute: 2 x 24 MFMA ----
#pragma unroll
        for (int c32 = 0; c32 < 2; c32++) {
            s16x8 a[2], b[12];
#pragma unroll
            for (int rt = 0; rt < 2; rt++) {
                int row = wr * 32 + rt * 16 + m16;
                int g0 = c32 * 8 + quad * 2;
                float4 lo = *(const float4*)&Asf[row * 64 + ((g0 ^ (row & 7)) << 2)];
                float4 hi = *(const float4*)&Asf[row * 64 + (((g0 + 1) ^ (row & 7)) << 2)];
                s16x8 av;
                av[0] = (short)f2bf(lo.x); av[1] = (short)f2bf(lo.y);
                av[2] = (short)f2bf(lo.z); av[3] = (short)f2bf(lo.w);
                av[4] = (short)f2bf(hi.x); av[5] = (short)f2bf(hi.y);
                av[6] = (short)f2bf(hi.z); av[7] = (short)f2bf(hi.w);
                a[rt] = av;
            }
#pragma unroll
            for (int ct = 0; ct < 12; ct++) {
                int col = wc * 192 + ct * 16 + m16;
                b[ct] = *(const s16x8*)&Bsu[col * 64 + (((c32 * 4 + quad) ^ (col & 7)) << 3)];
            }
#pragma unroll
            for (int rt = 0; rt < 2; rt++)
#pragma unroll
                for (int ct = 0; ct < 12; ct++) acc[rt][ct] = MFMA16(a[rt], b[ct], acc[rt][ct]);
        }
        __syncthreads();
    }

    // ---- epilogue: C-tile -> LDS, then Q rows + K/V image stores straight from LDS ----
#pragma unroll
    for (int rt = 0; rt < 2; rt++)
#pragma unroll
        for (int ct = 0; ct < 12; ct++)
#pragma unroll
            for (int rg = 0; rg < 4; rg++)
                sm.Cs[wr * 32 + rt * 16 + quad * 4 + rg][wc * 192 + ct * 16 + m16] = f2bf(acc[rt][ct][rg]);
    __syncthreads();

    const int bq = mt >> 7;            // batch
    const int n0 = (mt & 127) * 64;    // block's first token within batch (multiple of 64)
    const size_t kioff2[4] = {KI0_OFF, KG1_OFF, KG2_OFF, KG3_OFF};
    const size_t vtoff2[4] = {VT0_OFF, VT1_OFF, VT2_OFF, VT3_OFF};

    // Q: 1024 dense 16B stores
#pragma unroll
    for (int i = 0; i < 4; i++) {
        int id = tid + 256 * i;
        int row = id >> 4, ch = id & 15;
        *(s16x8*)(Q + ((size_t)(mt * 64 + row)) * 128 + ch * 8) = *(const s16x8*)&sm.Cs[row][ch * 8];
    }
    // K images [jt][hchunk][64 key][8 h]: 1920 stores, key-major within each (c,hc) run -> dense
#pragma unroll
    for (int i = 0; i < 8; i++) {
        int id = tid + 256 * i;
        if (id < 1920) {
            int c, e;
            if (id < 1024)      { c = 0; e = id; }
            else if (id < 1536) { c = 1; e = id - 1024; }
            else if (id < 1792) { c = 2; e = id - 1536; }
            else                { c = 3; e = id - 1792; }
            int hc = e >> (6 - c);
            int rloc = (e & ((64 >> c) - 1)) << c;     // token row in block, multiple of r
            int n = n0 + rloc;
            int s2 = n >> (10 + c);
            int key = (n & ((1024 << c) - 1)) >> c;
            int segc2 = bq * (8 >> c) + s2;
            unsigned short* Ki = (unsigned short*)(ws + kioff2[c]) + (size_t)segc2 * 131072;
            *(s16x8*)(Ki + (size_t)(key >> 6) * 8192 + hc * 512 + (key & 63) * 8) =
                *(const s16x8*)&sm.Cs[rloc][128 + hc * 8];
        }
    }
    // V images [jt][kchunk][128 h][8 key]: 1920 stores, 8x8 transpose gathered from LDS
#pragma unroll
    for (int i = 0; i < 8; i++) {
        int id = tid + 256 * i;
        if (id < 1920) {
            int c, e;
            if (id < 1024)      { c = 0; e = id; }
            else if (id < 1536) { c = 1; e = id - 1024; }
            else if (id < 1792) { c = 2; e = id - 1536; }
            else                { c = 3; e = id - 1792; }
            int g = e >> 7;                            // 8-key group within block
            int h = e & 127;
            int s2 = n0 >> (10 + c);
            int key0 = ((n0 & ((1024 << c) - 1)) >> c) + g * 8;
            int segc2 = bq * (8 >> c) + s2;
            s16x8 o;
#pragma unroll
            for (int i2 = 0; i2 < 8; i2++) o[i2] = sm.Cs[(g * 8 + i2) << c][256 + h];
            unsigned short* Vt2 = (unsigned short*)(ws + vtoff2[c]) + (size_t)segc2 * 131072;
            *(s16x8*)(Vt2 + (size_t)(key0 >> 6) * 8192 + ((key0 & 63) >> 3) * 1024 + h * 8) = o;
        }
    }
}

// ---------------- attention: paired q-tiles (p, 15-p), linear-image K/V staging, packed bf16 O ----
__global__ __launch_bounds__(256, 3) void k_attn(char* __restrict__ ws) {
    __shared__ s16x8 KsV[1024];              // [hchunk=c4*4+qd][64 key] fragment-order, 16 KB
    __shared__ s16x8 VsV[1024];              // [vchunk][64 h]          fragment-order, 16 KB
    __shared__ unsigned short Ps[128][72];   // P rows (wave-private); reused as O-pack buffer

    const int segid = blockIdx.x & 63;
    if (segid >= 60) return;
    const int p = blockIdx.x >> 6;           // pair index 0..7
    int c, b, s;
    if (segid < 32)      { c = 0; b = segid >> 3;        s = segid & 7; }
    else if (segid < 48) { c = 1; b = (segid - 32) >> 2; s = (segid - 32) & 3; }
    else if (segid < 56) { c = 2; b = (segid - 48) >> 1; s = (segid - 48) & 1; }
    else                 { c = 3; b = segid - 56;        s = 0; }
    const int S = 8 >> c, r = 1 << c, wseg = 1024 << c;
    const int segc = b * S + s;
    const int qtL = p, qtH = 15 - p, J = qtH + 1;

    const size_t vtoff[4] = {VT0_OFF, VT1_OFF, VT2_OFF, VT3_OFF};
    const size_t ooff[4]  = {O0_OFF, O1_OFF, O2_OFF, O3_OFF};
    const size_t loff[4]  = {L0_OFF, L1_OFF, L2_OFF, L3_OFF};
    const size_t kioff[4] = {KI0_OFF, KG1_OFF, KG2_OFF, KG3_OFF};
    const unsigned short* Q  = (const unsigned short*)(ws + QKV_OFF);
    const unsigned short* Kg = (const unsigned short*)(ws + kioff[c]) + (size_t)segc * 131072;
    const unsigned short* Vt = (const unsigned short*)(ws + vtoff[c]) + (size_t)segc * 131072;
    unsigned short* Ob = (unsigned short*)(ws + ooff[c]) + (size_t)segc * 1024 * 128;
    float* Lb = (float*)(ws + loff[c]) + (size_t)segc * 1024;

    const int tid = threadIdx.x, lane = tid & 63, wv = tid >> 6;
    const int quad = lane >> 4, m16 = lane & 15;
    const float SCE = 0.08838834764831845f;  // 1/sqrt(128)

    s16x8 qfL[4], qfH[4];
    {
        int tokL = s * wseg + (qtL * 64 + wv * 16 + m16) * r;
        int tokH = s * wseg + (qtH * 64 + wv * 16 + m16) * r;
        const unsigned short* qpL = Q + ((size_t)(b * 8192 + tokL)) * 128;
        const unsigned short* qpH = Q + ((size_t)(b * 8192 + tokH)) * 128;
#pragma unroll
        for (int c4 = 0; c4 < 4; c4++) {
            qfL[c4] = *(const s16x8*)(qpL + c4 * 32 + quad * 8);
            qfH[c4] = *(const s16x8*)(qpH + c4 * 32 + quad * 8);
        }
    }
    f32x4 oaccL[8], oaccH[8];
#pragma unroll
    for (int i = 0; i < 8; i++) { oaccL[i] = (f32x4)0.f; oaccH[i] = (f32x4)0.f; }
    float lsumL[4] = {}, lsumH[4] = {};

    for (int j = 0; j < J; j++) {
        const unsigned short* Kgt = Kg + (size_t)j * 8192;
        const unsigned short* Vtt = Vt + (size_t)j * 8192;
        // linear image copy: each inst = dense 1 KB (global) -> LDS base + lane*16
#pragma unroll
        for (int t = 0; t < 8; t++) {
            int id = wv * 8 + t;
            if (id < 16) {
                GLOAD_LDS16(Kgt + (size_t)id * 512 + lane * 8, &KsV[id * 64]);
            } else {
                int v = id - 16;
                GLOAD_LDS16(Vtt + (size_t)v * 512 + lane * 8, &VsV[v * 64]);
            }
        }
        __syncthreads();

        const bool lowA = (j <= qtL);
        const bool dgL = (j == qtL), dgH = (j == qtH);
        const int rbase = wv * 16 + quad * 4;
#pragma unroll
        for (int ct = 0; ct < 4; ct++) {
            f32x4 sL = (f32x4)0.f, sH = (f32x4)0.f;
#pragma unroll
            for (int c4 = 0; c4 < 4; c4++) {
                s16x8 kf = KsV[(c4 * 4 + quad) * 64 + ct * 16 + m16];
                if (lowA) sL = MFMA16(qfL[c4], kf, sL);
                sH = MFMA16(qfH[c4], kf, sH);
            }
            int colL = ct * 16 + m16;
            if (lowA) {
#pragma unroll
                for (int rg = 0; rg < 4; rg++) {
                    float pv = __expf(sL[rg] * SCE);
                    if (dgL && colL > rbase + rg) pv = 0.f;
                    lsumL[rg] += pv;
                    Ps[rbase + rg][colL] = f2bf(pv);
                }
            }
#pragma unroll
            for (int rg = 0; rg < 4; rg++) {
                float pv = __expf(sH[rg] * SCE);
                if (dgH && colL > rbase + rg) pv = 0.f;
                lsumH[rg] += pv;
                Ps[64 + rbase + rg][colL] = f2bf(pv);
            }
        }
#pragma unroll
        for (int kc = 0; kc < 2; kc++) {
            s16x8 aH = *(const s16x8*)&Ps[64 + wv * 16 + m16][kc * 32 + quad * 8];
            s16x8 aL;
            if (lowA) aL = *(const s16x8*)&Ps[wv * 16 + m16][kc * 32 + quad * 8];
#pragma unroll
            for (int nt = 0; nt < 8; nt++) {
                s16x8 bv = VsV[(kc * 4 + quad) * 128 + nt * 16 + m16];
                if (lowA) oaccL[nt] = MFMA16(aL, bv, oaccL[nt]);
                oaccH[nt] = MFMA16(aH, bv, oaccH[nt]);
            }
        }
        __syncthreads();
    }

#pragma unroll
    for (int rg = 0; rg < 4; rg++) {
        float vL = lsumL[rg], vH = lsumH[rg];
        vL += __shfl_xor(vL, 1); vL += __shfl_xor(vL, 2);
        vL += __shfl_xor(vL, 4); vL += __shfl_xor(vL, 8);
        vH += __shfl_xor(vH, 1); vH += __shfl_xor(vH, 2);
        vH += __shfl_xor(vH, 4); vH += __shfl_xor(vH, 8);
        lsumL[rg] = vL; lsumH[rg] = vH;
    }
    // ---- O epilogue: pack to bf16 in LDS (reuse Ps, flat [64][128]), dense NT 16B stores ----
    unsigned short* Pf = &Ps[0][0];
    unsigned short* ObL = Ob + (size_t)(qtL * 64) * 128;
    unsigned short* ObH = Ob + (size_t)(qtH * 64) * 128;
#pragma unroll
    for (int nt = 0; nt < 8; nt++)
#pragma unroll
        for (int rg = 0; rg < 4; rg++) {
            int rl = wv * 16 + quad * 4 + rg;
            Pf[rl * 128 + nt * 16 + m16] = f2bf(oaccL[nt][rg]);
        }
    __syncthreads();
#pragma unroll
    for (int i = 0; i < 4; i++) {
        int u = tid + 256 * i;                 // 1024 s16x8 units
        __builtin_nontemporal_store(*(const s16x8*)&Pf[u * 8], (s16x8*)(ObL + (size_t)u * 8));
    }
    __syncthreads();
#pragma unroll
    for (int nt = 0; nt < 8; nt++)
#pragma unroll
        for (int rg = 0; rg < 4; rg++) {
            int rl = wv * 16 + quad * 4 + rg;
            Pf[rl * 128 + nt * 16 + m16] = f2bf(oaccH[nt][rg]);
        }
    __syncthreads();
#pragma unroll
    for (int i = 0; i < 4; i++) {
        int u = tid + 256 * i;
        __builtin_nontemporal_store(*(const s16x8*)&Pf[u * 8], (s16x8*)(ObH + (size_t)u * 8));
    }
    if (m16 == 0) {
#pragma unroll
        for (int rg = 0; rg < 4; rg++) {
            int rl = wv * 16 + quad * 4 + rg;
            Lb[qtL * 64 + rl] = lsumL[rg];
            Lb[qtH * 64 + rl] = lsumH[rg];
        }
    }
}

// ---------------- cross-config combine: out = sum_c O_c / sum_c L_c (O stored bf16, NT reads) ----
__global__ __launch_bounds__(256) void k_combine(const char* __restrict__ ws, float* __restrict__ out) {
    int gid = blockIdx.x * 256 + threadIdx.x;
    int rown = gid >> 5;
    int h4 = (gid & 31) * 4;
    int b = rown >> 13, n = rown & 8191;
    const size_t ooff[4] = {O0_OFF, O1_OFF, O2_OFF, O3_OFF};
    const size_t loff[4] = {L0_OFF, L1_OFF, L2_OFF, L3_OFF};
    float denom = 0.f;
    f32x4 acc = (f32x4)0.f;
#pragma unroll
    for (int c = 0; c < 4; c++) {
        if ((n & ((1 << c) - 1)) == 0) {
            int s = n >> (10 + c);
            int i = (n & ((1024 << c) - 1)) >> c;
            int rowc = b * (8192 >> c) + (s << 10) + i;
            denom += *((const float*)(ws + loff[c]) + rowc);
            s16x4 o = __builtin_nontemporal_load(
                (const s16x4*)((const unsigned short*)(ws + ooff[c]) + (size_t)rowc * 128 + h4));
            acc.x += bf2f((unsigned short)o[0]); acc.y += bf2f((unsigned short)o[1]);
            acc.z += bf2f((unsigned short)o[2]); acc.w += bf2f((unsigned short)o[3]);
        }
    }
    float inv = 1.f / denom;
    f32x4 res = acc * inv;
    __builtin_nontemporal_store(res, (f32x4*)(out + (size_t)rown * 128 + h4));
}

extern "C" void kernel_launch(void* const* d_in, const int* in_sizes, int n_in,
                              void* d_out, int out_size, void* d_ws, size_t ws_size,
                              hipStream_t stream) {
    const float* x  = (const float*)d_in[0];
    const float* Wq = (const float*)d_in[1];
    const float* Wk = (const float*)d_in[2];
    const float* Wv = (const float*)d_in[3];
    char* ws = (char*)d_ws;
    unsigned short* Wt = (unsigned short*)(ws + WT_OFF);

    k_wt<<<1536, 256, 0, stream>>>(Wq, Wk, Wv, Wt);
    k_qkv<<<512, 256, 0, stream>>>(x, Wt, ws);
    k_attn<<<512, 256, 0, stream>>>(ws);
    k_combine<<<4096, 256, 0, stream>>>(ws, (float*)d_out);
}

// Round 10
// 270.557 us; speedup vs baseline: 1.3692x; 1.3692x over previous
//
#include <hip/hip_runtime.h>

typedef __attribute__((ext_vector_type(8))) short s16x8;
typedef __attribute__((ext_vector_type(4))) short s16x4;
typedef __attribute__((ext_vector_type(4))) float f32x4;

#define MFMA16(a,b,c) __builtin_amdgcn_mfma_f32_16x16x32_bf16((a),(b),(c),0,0,0)

// async global->LDS, 16B per lane; LDS dest is wave-uniform base + lane*16
#define GLOAD_LDS16(g, l) \
    __builtin_amdgcn_global_load_lds((const __attribute__((address_space(1))) void*)(g), \
                                     (__attribute__((address_space(3))) void*)(l), 16, 0, 0)

__device__ __forceinline__ unsigned short f2bf(float f) {
    unsigned u = __builtin_bit_cast(unsigned, f);
    u = (u + 0x7FFFu + ((u >> 16) & 1u)) >> 16;
    return (unsigned short)u;
}

// ---------------- ws layout (bytes), ~86 MB of >=512 MB ----------------
#define MB ((size_t)1 << 20)
#define WT_OFF   ((size_t)0)        // Wt[384][1024] bf16 (row = mat*128+h)
#define QKV_OFF  (1*MB)             // Q only: [32768][128] bf16 = 8 MB (K/V never materialized)
#define VT0_OFF  (25*MB)            // per-config V image: [seg][16 jt][8 kchunk][128 h][8 key] bf16
#define VT1_OFF  (33*MB)
#define VT2_OFF  (37*MB)
#define VT3_OFF  (39*MB)
#define KG1_OFF  (40*MB)            // per-config K image: [seg][16 jt][16 hchunk][64 key][8 h] bf16
#define KG2_OFF  (44*MB)
#define KG3_OFF  (46*MB)
#define O0_OFF   (47*MB)            // per-config unnormalized O fp32 [seg*1024][128] (NT-streamed)
#define O1_OFF   (63*MB)
#define O2_OFF   (71*MB)
#define O3_OFF   (75*MB)
#define L0_OFF   (77*MB)            // per-config denominators fp32
#define L1_OFF   (L0_OFF + (size_t)131072)
#define L2_OFF   (L1_OFF + (size_t)65536)
#define L3_OFF   (L2_OFF + (size_t)32768)
#define KI0_OFF  (78*MB)            // c0 K image, 8 MB

// ---------------- W transpose: Wt[mat*128+h][c] = bf16(W[c][h]) ----------------
__global__ __launch_bounds__(256) void k_wt(const float* __restrict__ Wq, const float* __restrict__ Wk,
                                            const float* __restrict__ Wv, unsigned short* __restrict__ Wt) {
    int id = blockIdx.x * 256 + threadIdx.x;
    int mat = id >> 17;
    int rem = id & 131071;
    int h = rem >> 10, c = rem & 1023;
    const float* W = (mat == 0) ? Wq : (mat == 1) ? Wk : Wv;
    Wt[id] = f2bf(W[c * 128 + h]);
}

// ---------------- fused QKV GEMM + gather: writes Q rows and K/V images DIRECTLY ----------------
// [32768 x 1024] @ [1024 x 384]; epilogue scatters K/V from the LDS C-tile into the exact
// fragment-order images the attention kernel stages from (8-key groups never cross a 64-row block).
__global__ __launch_bounds__(256, 2) void k_qkv(const float* __restrict__ x,
                                                const unsigned short* __restrict__ Wt,
                                                char* __restrict__ ws) {
    union SMem {
        struct { float As[64][64]; unsigned short Bs[384][64]; } s;  // 16 KB + 48 KB
        unsigned short Cs[64][392];                                   // epilogue staging, 49 KB
    };
    __shared__ SMem sm;
    float* Asf = &sm.s.As[0][0];
    unsigned short* Bsu = &sm.s.Bs[0][0];
    unsigned short* Q = (unsigned short*)(ws + QKV_OFF);

    const int mt = blockIdx.x;        // 0..511, 64-row m-tile
    const int tid = threadIdx.x, lane = tid & 63, wv = tid >> 6;
    const int quad = lane >> 4, m16 = lane & 15;
    const int wr = wv >> 1, wc = wv & 1;     // wave tile: rows wr*32.., cols wc*192..
    const float* xb = x + (size_t)mt * 64 * 1024;

    f32x4 acc[2][12];
#pragma unroll
    for (int i = 0; i < 2; i++)
#pragma unroll
        for (int j = 0; j < 12; j++) acc[i][j] = (f32x4)0.f;

    for (int kk = 0; kk < 1024; kk += 64) {
        // ---- stage A (x, fp32): 16 KB = 16 insts, 4/wave. phys group = logical ^ (row&7) ----
#pragma unroll
        for (int t = 0; t < 4; t++) {
            int id = wv * 4 + t;                       // 0..15, wave-uniform
            int row = id * 4 + (lane >> 4);
            int gl = (lane & 15) ^ (row & 7);          // logical 16B-group this lane fetches
            GLOAD_LDS16(xb + (size_t)row * 1024 + kk + gl * 4, (char*)Asf + id * 1024);
        }
        // ---- stage B (Wt, bf16): 48 KB = 48 insts, 12/wave. phys group = logical ^ (col&7) ----
#pragma unroll
        for (int t = 0; t < 12; t++) {
            int id = wv * 12 + t;                      // 0..47
            int col = id * 8 + (lane >> 3);
            int gl = (lane & 7) ^ (lane >> 3);         // (col&7) == lane>>3 here
            GLOAD_LDS16(Wt + (size_t)col * 1024 + kk + gl * 8, (char*)Bsu + id * 1024);
        }
        __syncthreads();
        // ---- compute: 2 x 24 MFMA ----
#pragma unroll
        for (int c32 = 0; c32 < 2; c32++) {
            s16x8 a[2], b[12];
#pragma unroll
            for (int rt = 0; rt < 2; rt++) {
                int row = wr * 32 + rt * 16 + m16;
                int g0 = c32 * 8 + quad * 2;
                float4 lo = *(const float4*)&Asf[row * 64 + ((g0 ^ (row & 7)) << 2)];
                float4 hi = *(const float4*)&Asf[row * 64 + (((g0 + 1) ^ (row & 7)) << 2)];
                s16x8 av;
                av[0] = (short)f2bf(lo.x); av[1] = (short)f2bf(lo.y);
                av[2] = (short)f2bf(lo.z); av[3] = (short)f2bf(lo.w);
                av[4] = (short)f2bf(hi.x); av[5] = (short)f2bf(hi.y);
                av[6] = (short)f2bf(hi.z); av[7] = (short)f2bf(hi.w);
                a[rt] = av;
            }
#pragma unroll
            for (int ct = 0; ct < 12; ct++) {
                int col = wc * 192 + ct * 16 + m16;
                b[ct] = *(const s16x8*)&Bsu[col * 64 + (((c32 * 4 + quad) ^ (col & 7)) << 3)];
            }
#pragma unroll
            for (int rt = 0; rt < 2; rt++)
#pragma unroll
                for (int ct = 0; ct < 12; ct++) acc[rt][ct] = MFMA16(a[rt], b[ct], acc[rt][ct]);
        }
        __syncthreads();
    }

    // ---- epilogue: C-tile -> LDS, then Q rows + K/V image stores straight from LDS ----
#pragma unroll
    for (int rt = 0; rt < 2; rt++)
#pragma unroll
        for (int ct = 0; ct < 12; ct++)
#pragma unroll
            for (int rg = 0; rg < 4; rg++)
                sm.Cs[wr * 32 + rt * 16 + quad * 4 + rg][wc * 192 + ct * 16 + m16] = f2bf(acc[rt][ct][rg]);
    __syncthreads();

    const int bq = mt >> 7;            // batch
    const int n0 = (mt & 127) * 64;    // block's first token within batch (multiple of 64)
    const size_t kioff2[4] = {KI0_OFF, KG1_OFF, KG2_OFF, KG3_OFF};
    const size_t vtoff2[4] = {VT0_OFF, VT1_OFF, VT2_OFF, VT3_OFF};

    // Q: 1024 dense 16B stores
#pragma unroll
    for (int i = 0; i < 4; i++) {
        int id = tid + 256 * i;
        int row = id >> 4, ch = id & 15;
        *(s16x8*)(Q + ((size_t)(mt * 64 + row)) * 128 + ch * 8) = *(const s16x8*)&sm.Cs[row][ch * 8];
    }
    // K images [jt][hchunk][64 key][8 h]: 1920 stores, key-major within each (c,hc) run -> dense
#pragma unroll
    for (int i = 0; i < 8; i++) {
        int id = tid + 256 * i;
        if (id < 1920) {
            int c, e;
            if (id < 1024)      { c = 0; e = id; }
            else if (id < 1536) { c = 1; e = id - 1024; }
            else if (id < 1792) { c = 2; e = id - 1536; }
            else                { c = 3; e = id - 1792; }
            int hc = e >> (6 - c);
            int rloc = (e & ((64 >> c) - 1)) << c;     // token row in block, multiple of r
            int n = n0 + rloc;
            int s2 = n >> (10 + c);
            int key = (n & ((1024 << c) - 1)) >> c;
            int segc2 = bq * (8 >> c) + s2;
            unsigned short* Ki = (unsigned short*)(ws + kioff2[c]) + (size_t)segc2 * 131072;
            *(s16x8*)(Ki + (size_t)(key >> 6) * 8192 + hc * 512 + (key & 63) * 8) =
                *(const s16x8*)&sm.Cs[rloc][128 + hc * 8];
        }
    }
    // V images [jt][kchunk][128 h][8 key]: 1920 stores, 8x8 transpose gathered from LDS
#pragma unroll
    for (int i = 0; i < 8; i++) {
        int id = tid + 256 * i;
        if (id < 1920) {
            int c, e;
            if (id < 1024)      { c = 0; e = id; }
            else if (id < 1536) { c = 1; e = id - 1024; }
            else if (id < 1792) { c = 2; e = id - 1536; }
            else                { c = 3; e = id - 1792; }
            int g = e >> 7;                            // 8-key group within block
            int h = e & 127;
            int s2 = n0 >> (10 + c);
            int key0 = ((n0 & ((1024 << c) - 1)) >> c) + g * 8;
            int segc2 = bq * (8 >> c) + s2;
            s16x8 o;
#pragma unroll
            for (int i2 = 0; i2 < 8; i2++) o[i2] = sm.Cs[(g * 8 + i2) << c][256 + h];
            unsigned short* Vt2 = (unsigned short*)(ws + vtoff2[c]) + (size_t)segc2 * 131072;
            *(s16x8*)(Vt2 + (size_t)(key0 >> 6) * 8192 + ((key0 & 63) >> 3) * 1024 + h * 8) = o;
        }
    }
}

// ---------------- attention: paired q-tiles (p, 15-p), linear-image K/V staging, NT fp32 O ----
__global__ __launch_bounds__(256, 3) void k_attn(char* __restrict__ ws) {
    __shared__ s16x8 KsV[1024];              // [hchunk=c4*4+qd][64 key] fragment-order, 16 KB
    __shared__ s16x8 VsV[1024];              // [vchunk][64 h]          fragment-order, 16 KB
    __shared__ unsigned short Ps[128][72];   // P rows 0..63 low tile, 64..127 high; wave-private rows

    const int segid = blockIdx.x & 63;
    if (segid >= 60) return;
    const int p = blockIdx.x >> 6;           // pair index 0..7
    int c, b, s;
    if (segid < 32)      { c = 0; b = segid >> 3;        s = segid & 7; }
    else if (segid < 48) { c = 1; b = (segid - 32) >> 2; s = (segid - 32) & 3; }
    else if (segid < 56) { c = 2; b = (segid - 48) >> 1; s = (segid - 48) & 1; }
    else                 { c = 3; b = segid - 56;        s = 0; }
    const int S = 8 >> c, r = 1 << c, wseg = 1024 << c;
    const int segc = b * S + s;
    const int qtL = p, qtH = 15 - p, J = qtH + 1;

    const size_t vtoff[4] = {VT0_OFF, VT1_OFF, VT2_OFF, VT3_OFF};
    const size_t ooff[4]  = {O0_OFF, O1_OFF, O2_OFF, O3_OFF};
    const size_t loff[4]  = {L0_OFF, L1_OFF, L2_OFF, L3_OFF};
    const size_t kioff[4] = {KI0_OFF, KG1_OFF, KG2_OFF, KG3_OFF};
    const unsigned short* Q  = (const unsigned short*)(ws + QKV_OFF);
    const unsigned short* Kg = (const unsigned short*)(ws + kioff[c]) + (size_t)segc * 131072;
    const unsigned short* Vt = (const unsigned short*)(ws + vtoff[c]) + (size_t)segc * 131072;
    float* Ob = (float*)(ws + ooff[c]) + (size_t)segc * 1024 * 128;
    float* Lb = (float*)(ws + loff[c]) + (size_t)segc * 1024;

    const int tid = threadIdx.x, lane = tid & 63, wv = tid >> 6;
    const int quad = lane >> 4, m16 = lane & 15;
    const float SCE = 0.08838834764831845f;  // 1/sqrt(128)

    s16x8 qfL[4], qfH[4];
    {
        int tokL = s * wseg + (qtL * 64 + wv * 16 + m16) * r;
        int tokH = s * wseg + (qtH * 64 + wv * 16 + m16) * r;
        const unsigned short* qpL = Q + ((size_t)(b * 8192 + tokL)) * 128;
        const unsigned short* qpH = Q + ((size_t)(b * 8192 + tokH)) * 128;
#pragma unroll
        for (int c4 = 0; c4 < 4; c4++) {
            qfL[c4] = *(const s16x8*)(qpL + c4 * 32 + quad * 8);
            qfH[c4] = *(const s16x8*)(qpH + c4 * 32 + quad * 8);
        }
    }
    f32x4 oaccL[8], oaccH[8];
#pragma unroll
    for (int i = 0; i < 8; i++) { oaccL[i] = (f32x4)0.f; oaccH[i] = (f32x4)0.f; }
    float lsumL[4] = {}, lsumH[4] = {};

    for (int j = 0; j < J; j++) {
        const unsigned short* Kgt = Kg + (size_t)j * 8192;
        const unsigned short* Vtt = Vt + (size_t)j * 8192;
        // linear image copy: each inst = dense 1 KB (global) -> LDS base + lane*16
#pragma unroll
        for (int t = 0; t < 8; t++) {
            int id = wv * 8 + t;
            if (id < 16) {
                GLOAD_LDS16(Kgt + (size_t)id * 512 + lane * 8, &KsV[id * 64]);
            } else {
                int v = id - 16;
                GLOAD_LDS16(Vtt + (size_t)v * 512 + lane * 8, &VsV[v * 64]);
            }
        }
        __syncthreads();

        const bool lowA = (j <= qtL);
        const bool dgL = (j == qtL), dgH = (j == qtH);
        const int rbase = wv * 16 + quad * 4;
#pragma unroll
        for (int ct = 0; ct < 4; ct++) {
            f32x4 sL = (f32x4)0.f, sH = (f32x4)0.f;
#pragma unroll
            for (int c4 = 0; c4 < 4; c4++) {
                s16x8 kf = KsV[(c4 * 4 + quad) * 64 + ct * 16 + m16];
                if (lowA) sL = MFMA16(qfL[c4], kf, sL);
                sH = MFMA16(qfH[c4], kf, sH);
            }
            int colL = ct * 16 + m16;
            if (lowA) {
#pragma unroll
                for (int rg = 0; rg < 4; rg++) {
                    float pv = __expf(sL[rg] * SCE);
                    if (dgL && colL > rbase + rg) pv = 0.f;
                    lsumL[rg] += pv;
                    Ps[rbase + rg][colL] = f2bf(pv);
                }
            }
#pragma unroll
            for (int rg = 0; rg < 4; rg++) {
                float pv = __expf(sH[rg] * SCE);
                if (dgH && colL > rbase + rg) pv = 0.f;
                lsumH[rg] += pv;
                Ps[64 + rbase + rg][colL] = f2bf(pv);
            }
        }
#pragma unroll
        for (int kc = 0; kc < 2; kc++) {
            s16x8 aH = *(const s16x8*)&Ps[64 + wv * 16 + m16][kc * 32 + quad * 8];
            s16x8 aL;
            if (lowA) aL = *(const s16x8*)&Ps[wv * 16 + m16][kc * 32 + quad * 8];
#pragma unroll
            for (int nt = 0; nt < 8; nt++) {
                s16x8 bv = VsV[(kc * 4 + quad) * 128 + nt * 16 + m16];
                if (lowA) oaccL[nt] = MFMA16(aL, bv, oaccL[nt]);
                oaccH[nt] = MFMA16(aH, bv, oaccH[nt]);
            }
        }
        __syncthreads();
    }

#pragma unroll
    for (int rg = 0; rg < 4; rg++) {
        float vL = lsumL[rg], vH = lsumH[rg];
        vL += __shfl_xor(vL, 1); vL += __shfl_xor(vL, 2);
        vL += __shfl_xor(vL, 4); vL += __shfl_xor(vL, 8);
        vH += __shfl_xor(vH, 1); vH += __shfl_xor(vH, 2);
        vH += __shfl_xor(vH, 4); vH += __shfl_xor(vH, 8);
        lsumL[rg] = vL; lsumH[rg] = vH;
    }
    float* OcL = Ob + (size_t)(qtL * 64) * 128;
    float* OcH = Ob + (size_t)(qtH * 64) * 128;
#pragma unroll
    for (int nt = 0; nt < 8; nt++)
#pragma unroll
        for (int rg = 0; rg < 4; rg++) {
            int rl = wv * 16 + quad * 4 + rg;
            __builtin_nontemporal_store(oaccL[nt][rg], &OcL[(size_t)rl * 128 + nt * 16 + m16]);
            __builtin_nontemporal_store(oaccH[nt][rg], &OcH[(size_t)rl * 128 + nt * 16 + m16]);
        }
    if (m16 == 0) {
#pragma unroll
        for (int rg = 0; rg < 4; rg++) {
            int rl = wv * 16 + quad * 4 + rg;
            Lb[qtL * 64 + rl] = lsumL[rg];
            Lb[qtH * 64 + rl] = lsumH[rg];
        }
    }
}

// ---------------- cross-config combine: out = sum_c O_c / sum_c L_c (NT O reads) ----------------
__global__ __launch_bounds__(256) void k_combine(const char* __restrict__ ws, float* __restrict__ out) {
    int gid = blockIdx.x * 256 + threadIdx.x;
    int rown = gid >> 5;
    int h4 = (gid & 31) * 4;
    int b = rown >> 13, n = rown & 8191;
    const size_t ooff[4] = {O0_OFF, O1_OFF, O2_OFF, O3_OFF};
    const size_t loff[4] = {L0_OFF, L1_OFF, L2_OFF, L3_OFF};
    float denom = 0.f;
    f32x4 acc = (f32x4)0.f;
#pragma unroll
    for (int c = 0; c < 4; c++) {
        if ((n & ((1 << c) - 1)) == 0) {
            int s = n >> (10 + c);
            int i = (n & ((1024 << c) - 1)) >> c;
            int rowc = b * (8192 >> c) + (s << 10) + i;
            denom += *((const float*)(ws + loff[c]) + rowc);
            f32x4 o = __builtin_nontemporal_load(
                (const f32x4*)((const float*)(ws + ooff[c]) + (size_t)rowc * 128 + h4));
            acc += o;
        }
    }
    float inv = 1.f / denom;
    f32x4 res = acc * inv;
    __builtin_nontemporal_store(res, (f32x4*)(out + (size_t)rown * 128 + h4));
}

extern "C" void kernel_launch(void* const* d_in, const int* in_sizes, int n_in,
                              void* d_out, int out_size, void* d_ws, size_t ws_size,
                              hipStream_t stream) {
    const float* x  = (const float*)d_in[0];
    const float* Wq = (const float*)d_in[1];
    const float* Wk = (const float*)d_in[2];
    const float* Wv = (const float*)d_in[3];
    char* ws = (char*)d_ws;
    unsigned short* Wt = (unsigned short*)(ws + WT_OFF);

    k_wt<<<1536, 256, 0, stream>>>(Wq, Wk, Wv, Wt);
    k_qkv<<<512, 256, 0, stream>>>(x, Wt, ws);
    k_attn<<<512, 256, 0, stream>>>(ws);
    k_combine<<<4096, 256, 0, stream>>>(ws, (float*)d_out);
}